// Round 8
// baseline (309.629 us; speedup 1.0000x reference)
//
#include <hip/hip_runtime.h>
#include <float.h>
#include <limits.h>

#define NB     16
#define QLEN   32
#define HDIM   128
#define NPIDS  500
#define NDOCS  10000
#define DLEN   200
#define TOPK   100
#define VROW   (DLEN * HDIM)

typedef __bf16 bf16x8 __attribute__((ext_vector_type(8)));
typedef float  f32x16 __attribute__((ext_vector_type(16)));

// ---------------- Kernel 1: per-row sort + dedupe (dup -> -1) ----------------
__global__ __launch_bounds__(512) void dedupe_kernel(const int* __restrict__ pids,
                                                     const int* __restrict__ boundaries,
                                                     int* __restrict__ dpids) {
    __shared__ int s[512];
    const int b = blockIdx.x;
    const int t = threadIdx.x;
    const int lo = boundaries[0];

    int v = INT_MAX;
    if (t < NPIDS) {
        int p = pids[b * NPIDS + t] - lo;
        if (p < 0 || p >= NDOCS) p = -1;
        v = p;
    }
    s[t] = v;
    __syncthreads();

    for (int k = 2; k <= 512; k <<= 1) {
        for (int j = k >> 1; j > 0; j >>= 1) {
            int ixj = t ^ j;
            if (ixj > t) {
                int a = s[t], c = s[ixj];
                bool up = ((t & k) == 0);
                if ((a > c) == up) { s[t] = c; s[ixj] = a; }
            }
            __syncthreads();
        }
    }

    if (t < NPIDS) {
        int val = s[t];
        int o = val;
        if (val == INT_MAX) o = -1;
        else if (t > 0 && val == s[t - 1]) o = -1;
        dpids[b * NPIDS + t] = o;
    }
}

// 3-way bf16 split (round-to-nearest) — the R4-verified path (absmax 0.0).
// r1 = a - (float)h and r2 = r1 - (float)m are exact (Sterbenz).
__device__ __forceinline__ void split3(float a, __bf16& h, __bf16& m, __bf16& l) {
    h = (__bf16)a;
    float r1 = a - (float)h;
    m = (__bf16)r1;
    float r2 = r1 - (float)m;
    l = (__bf16)r2;
}

__device__ __forceinline__ void split3_pack8(const float4 c0, const float4 c1,
                                             bf16x8& H, bf16x8& M, bf16x8& L) {
    float f[8] = {c0.x, c0.y, c0.z, c0.w, c1.x, c1.y, c1.z, c1.w};
    bf16x8 Ht, Mt, Lt;
    #pragma unroll
    for (int j = 0; j < 8; ++j) {
        __bf16 hh, mm, ll;
        split3(f[j], hh, mm, ll);
        Ht[j] = hh; Mt[j] = mm; Lt[j] = ll;
    }
    H = Ht; M = Mt; L = Lt;
}

// ---------------- Kernel 2: MaxSim via split-bf16 MFMA ----------------
// Grid (63, 16): blockIdx.y = batch, blockIdx.x = 8-candidate group (tail
// block clamps its pairs to 496/498; duplicate waves write bit-identical
// scores — benign). Q limbs are computed once by wave 0 and shared in LDS in
// MFMA-fragment order [ks][limb][lane][16B] (lane-consecutive -> conflict-free
// ds_read_b128), freeing ~96 VGPR -> 3 waves/SIMD. V path identical to R7:
// depth-4 circular register prefetch, RN split3 limbs, MFMA order hh,hm,mh,hl,lh
// -> scores bit-identical to R4/R7.
__global__ __launch_bounds__(256, 3) void score_kernel(const float* __restrict__ qv,
                                                       const float* __restrict__ vectors,
                                                       const int* __restrict__ dpids,
                                                       float* __restrict__ scores) {
    const int t    = threadIdx.x;
    const int w    = t >> 6;
    const int lane = t & 63;
    const int row  = lane & 31;     // q-row for A, token-in-tile for B
    const int half = lane >> 5;     // k-half selector
    const int b    = blockIdx.y;

    int cs = blockIdx.x * 8 + w * 2;
    if (cs > NPIDS - 2) cs = NPIDS - 2;          // tail clamp (dup work, benign)
    const int cbase = b * NPIDS + cs;

    __shared__ __align__(16) unsigned char qlds[8][3][64][16];   // 24 KB

    if (t < 64) {
        // thread t builds fragment for lane t: rows via row=t&31, half=t>>5
        const float* qb = qv + ((size_t)b * QLEN + row) * HDIM + half * 8;
        #pragma unroll
        for (int ks = 0; ks < 8; ++ks) {
            const float4 a0 = *(const float4*)(qb + ks * 16);
            const float4 a1 = *(const float4*)(qb + ks * 16 + 4);
            bf16x8 H, M, L;
            split3_pack8(a0, a1, H, M, L);
            *(bf16x8*)qlds[ks][0][t] = H;
            *(bf16x8*)qlds[ks][1][t] = M;
            *(bf16x8*)qlds[ks][2][t] = L;
        }
    }
    __syncthreads();

    for (int ci = 0; ci < 2; ++ci) {
        const int c   = cbase + ci;
        const int pid = dpids[c];
        if (pid < 0) {
            if (lane == 0) scores[c] = -__builtin_inff();
            continue;
        }

        const float* vb = vectors + (size_t)pid * VROW + half * 8;

        float rmax[16];
        #pragma unroll
        for (int j = 0; j < 16; ++j) rmax[j] = -FLT_MAX;

        // ---- prologue: prefetch chunks 0..3 (tile 0, ks 0..3) ----
        const float* vt0 = vb + (size_t)row * HDIM;   // tile 0: tok = row < 200
        float4 pf[4][2];
        #pragma unroll
        for (int s = 0; s < 4; ++s) {
            pf[s][0] = *(const float4*)(vt0 + s * 16);
            pf[s][1] = *(const float4*)(vt0 + s * 16 + 4);
        }

        #pragma unroll 1
        for (int tile = 0; tile < 7; ++tile) {
            int tok = tile * 32 + row;
            if (tok > DLEN - 1) tok = DLEN - 1;            // dup token 199: max-safe
            const float* vt = vb + (size_t)tok * HDIM;
            int tokn = (tile + 1) * 32 + row;
            if (tokn > DLEN - 1) tokn = DLEN - 1;
            const float* vtn = vb + (size_t)tokn * HDIM;   // next tile base

            f32x16 acc;
            #pragma unroll
            for (int j = 0; j < 16; ++j) acc[j] = 0.0f;

            #pragma unroll
            for (int ks = 0; ks < 8; ++ks) {
                const int slot = ks & 3;                   // compile-time in unroll
                const float4 c0 = pf[slot][0];
                const float4 c1 = pf[slot][1];

                // issue chunk +4 into the freed slot
                if (ks < 4) {
                    pf[slot][0] = *(const float4*)(vt + (ks + 4) * 16);
                    pf[slot][1] = *(const float4*)(vt + (ks + 4) * 16 + 4);
                } else if (tile < 6) {
                    pf[slot][0] = *(const float4*)(vtn + (ks - 4) * 16);
                    pf[slot][1] = *(const float4*)(vtn + (ks - 4) * 16 + 4);
                }

                bf16x8 vh, vm, vl;
                split3_pack8(c0, c1, vh, vm, vl);

                const bf16x8 qh = *(const bf16x8*)qlds[ks][0][lane];
                const bf16x8 qm = *(const bf16x8*)qlds[ks][1][lane];
                const bf16x8 ql = *(const bf16x8*)qlds[ks][2][lane];

                acc = __builtin_amdgcn_mfma_f32_32x32x16_bf16(qh, vh, acc, 0, 0, 0);
                acc = __builtin_amdgcn_mfma_f32_32x32x16_bf16(qh, vm, acc, 0, 0, 0);
                acc = __builtin_amdgcn_mfma_f32_32x32x16_bf16(qm, vh, acc, 0, 0, 0);
                acc = __builtin_amdgcn_mfma_f32_32x32x16_bf16(qh, vl, acc, 0, 0, 0);
                acc = __builtin_amdgcn_mfma_f32_32x32x16_bf16(ql, vh, acc, 0, 0, 0);
            }

            #pragma unroll
            for (int j = 0; j < 16; ++j) rmax[j] = fmaxf(rmax[j], acc[j]);
        }

        // cross-lane max over the 32 token-columns per q-row, then double-sum.
        double dsum = 0.0;
        #pragma unroll
        for (int j = 0; j < 16; ++j) {
            float m = rmax[j];
            m = fmaxf(m, __shfl_xor(m, 1));
            m = fmaxf(m, __shfl_xor(m, 2));
            m = fmaxf(m, __shfl_xor(m, 4));
            m = fmaxf(m, __shfl_xor(m, 8));
            m = fmaxf(m, __shfl_xor(m, 16));
            dsum += (double)m;
        }
        dsum += __shfl_xor(dsum, 32);
        if (lane == 0) scores[c] = (float)dsum;
    }
}

// ---------------- Kernel 3: per-batch top-100 (sorted desc) ----------------
__global__ __launch_bounds__(512) void topk_kernel(const float* __restrict__ scores,
                                                   const int* __restrict__ dpids,
                                                   const int* __restrict__ boundaries,
                                                   float* __restrict__ out) {
    __shared__ float ss[512];
    __shared__ int   sp[512];
    const int b = blockIdx.x;
    const int t = threadIdx.x;
    const int lo = boundaries[0];

    float sc = -__builtin_inff();
    int   p  = -1;
    if (t < NPIDS) {
        p = dpids[b * NPIDS + t];
        sc = (p < 0) ? -__builtin_inff() : scores[b * NPIDS + t];
    }
    ss[t] = sc;
    sp[t] = p;
    __syncthreads();

    for (int k = 2; k <= 512; k <<= 1) {
        for (int j = k >> 1; j > 0; j >>= 1) {
            int ixj = t ^ j;
            if (ixj > t) {
                float a = ss[t], c = ss[ixj];
                bool down = ((t & k) == 0);
                bool swap = down ? (a < c) : (a > c);
                if (swap) {
                    int pa = sp[t], pc = sp[ixj];
                    ss[t] = c;   ss[ixj] = a;
                    sp[t] = pc;  sp[ixj] = pa;
                }
            }
            __syncthreads();
        }
    }

    if (t < TOPK) {
        out[b * TOPK + t] = ss[t];
        int pp = sp[t];
        out[NB * TOPK + b * TOPK + t] = (pp >= 0) ? (float)(pp + lo) : -1.0f;
    }
}

// ---------------- launch ----------------
extern "C" void kernel_launch(void* const* d_in, const int* in_sizes, int n_in,
                              void* d_out, int out_size, void* d_ws, size_t ws_size,
                              hipStream_t stream) {
    const float* qv        = (const float*)d_in[0];
    const int*   pids      = (const int*)d_in[1];
    const float* vectors   = (const float*)d_in[2];
    const int*   boundaries= (const int*)d_in[3];

    int*   dpids  = (int*)d_ws;
    float* scores = (float*)((char*)d_ws + 32768);

    dedupe_kernel<<<NB, 512, 0, stream>>>(pids, boundaries, dpids);
    dim3 sgrid((NPIDS + 7) / 8, NB);
    score_kernel <<<sgrid, 256, 0, stream>>>(qv, vectors, dpids, scores);
    topk_kernel  <<<NB, 512, 0, stream>>>(scores, dpids, boundaries, (float*)d_out);
}

// Round 9
// 169.738 us; speedup vs baseline: 1.8242x; 1.8242x over previous
//
#include <hip/hip_runtime.h>
#include <float.h>
#include <limits.h>

#define NB     16
#define QLEN   32
#define HDIM   128
#define NPIDS  500
#define NDOCS  10000
#define DLEN   200
#define TOPK   100
#define VROW   (DLEN * HDIM)

typedef __bf16 bf16x8 __attribute__((ext_vector_type(8)));
typedef float  f32x16 __attribute__((ext_vector_type(16)));

// ---------------- Kernel 1: per-row sort + dedupe (dup -> -1) ----------------
__global__ __launch_bounds__(512) void dedupe_kernel(const int* __restrict__ pids,
                                                     const int* __restrict__ boundaries,
                                                     int* __restrict__ dpids) {
    __shared__ int s[512];
    const int b = blockIdx.x;
    const int t = threadIdx.x;
    const int lo = boundaries[0];

    int v = INT_MAX;
    if (t < NPIDS) {
        int p = pids[b * NPIDS + t] - lo;
        if (p < 0 || p >= NDOCS) p = -1;
        v = p;
    }
    s[t] = v;
    __syncthreads();

    for (int k = 2; k <= 512; k <<= 1) {
        for (int j = k >> 1; j > 0; j >>= 1) {
            int ixj = t ^ j;
            if (ixj > t) {
                int a = s[t], c = s[ixj];
                bool up = ((t & k) == 0);
                if ((a > c) == up) { s[t] = c; s[ixj] = a; }
            }
            __syncthreads();
        }
    }

    if (t < NPIDS) {
        int val = s[t];
        int o = val;
        if (val == INT_MAX) o = -1;
        else if (t > 0 && val == s[t - 1]) o = -1;
        dpids[b * NPIDS + t] = o;
    }
}

// 3-way bf16 split (round-to-nearest) — the R4-verified path (absmax 0.0).
// r1 = a - (float)h and r2 = r1 - (float)m are exact (Sterbenz).
__device__ __forceinline__ void split3(float a, __bf16& h, __bf16& m, __bf16& l) {
    h = (__bf16)a;
    float r1 = a - (float)h;
    m = (__bf16)r1;
    float r2 = r1 - (float)m;
    l = (__bf16)r2;
}

__device__ __forceinline__ void split3_pack8(const float4 c0, const float4 c1,
                                             bf16x8& H, bf16x8& M, bf16x8& L) {
    float f[8] = {c0.x, c0.y, c0.z, c0.w, c1.x, c1.y, c1.z, c1.w};
    bf16x8 Ht, Mt, Lt;
    #pragma unroll
    for (int j = 0; j < 8; ++j) {
        __bf16 hh, mm, ll;
        split3(f[j], hh, mm, ll);
        Ht[j] = hh; Mt[j] = mm; Lt[j] = ll;
    }
    H = Ht; M = Mt; L = Lt;
}

// ---------------- Kernel 2: MaxSim via split-bf16 MFMA + depth-8 prefetch ----------------
// One wave per 2 consecutive candidates (same batch: 500 even, pairs aligned).
// Q limbs stationary in registers (96 VGPR — R8 showed LDS-Q regresses 2x).
// Numerics bit-identical to R4/R7 (RN split3 limbs, MFMA order hh,hm,mh,hl,lh).
// Depth-8 circular register prefetch: slot = ks; during tile t step ks we
// issue the same-ks chunk of tile t+1 — a full tile (~1150 cyc) of latency
// cover vs ~900 cyc HBM miss (depth-4's 576 cyc was the R7 stall residue).
__global__ __launch_bounds__(256, 2) void score_kernel(const float* __restrict__ qv,
                                                       const float* __restrict__ vectors,
                                                       const int* __restrict__ dpids,
                                                       float* __restrict__ scores) {
    const int t    = threadIdx.x;
    const int w    = t >> 6;
    const int lane = t & 63;
    const int row  = lane & 31;     // q-row for A, token-in-tile for B
    const int half = lane >> 5;     // k-half selector

    const int cbase = (blockIdx.x * 4 + w) * 2;
    const int b     = cbase / NPIDS;

    // ---- load + split Q fragments (stationary for both candidates) ----
    bf16x8 qh[8], qm[8], ql[8];
    {
        const float* qb = qv + ((size_t)b * QLEN + row) * HDIM + half * 8;
        #pragma unroll
        for (int ks = 0; ks < 8; ++ks) {
            const float4 a0 = *(const float4*)(qb + ks * 16);
            const float4 a1 = *(const float4*)(qb + ks * 16 + 4);
            split3_pack8(a0, a1, qh[ks], qm[ks], ql[ks]);
        }
    }

    for (int ci = 0; ci < 2; ++ci) {
        const int c   = cbase + ci;
        const int pid = dpids[c];
        if (pid < 0) {
            if (lane == 0) scores[c] = -__builtin_inff();
            continue;
        }

        const float* vb = vectors + (size_t)pid * VROW + half * 8;

        float rmax[16];
        #pragma unroll
        for (int j = 0; j < 16; ++j) rmax[j] = -FLT_MAX;

        // ---- prologue: prefetch the full tile 0 (chunks ks = 0..7) ----
        const float* vt0 = vb + (size_t)row * HDIM;   // tile 0: tok = row < 200
        float4 pf[8][2];
        #pragma unroll
        for (int s = 0; s < 8; ++s) {
            pf[s][0] = *(const float4*)(vt0 + s * 16);
            pf[s][1] = *(const float4*)(vt0 + s * 16 + 4);
        }

        #pragma unroll 1
        for (int tile = 0; tile < 7; ++tile) {
            int tokn = (tile + 1) * 32 + row;
            if (tokn > DLEN - 1) tokn = DLEN - 1;
            const float* vtn = vb + (size_t)tokn * HDIM;   // next tile base

            f32x16 acc;
            #pragma unroll
            for (int j = 0; j < 16; ++j) acc[j] = 0.0f;

            #pragma unroll
            for (int ks = 0; ks < 8; ++ks) {
                const float4 c0 = pf[ks][0];
                const float4 c1 = pf[ks][1];

                // issue the same-ks chunk of the next tile into the freed slot
                if (tile < 6) {
                    pf[ks][0] = *(const float4*)(vtn + ks * 16);
                    pf[ks][1] = *(const float4*)(vtn + ks * 16 + 4);
                }

                bf16x8 vh, vm, vl;
                split3_pack8(c0, c1, vh, vm, vl);
                acc = __builtin_amdgcn_mfma_f32_32x32x16_bf16(qh[ks], vh, acc, 0, 0, 0);
                acc = __builtin_amdgcn_mfma_f32_32x32x16_bf16(qh[ks], vm, acc, 0, 0, 0);
                acc = __builtin_amdgcn_mfma_f32_32x32x16_bf16(qm[ks], vh, acc, 0, 0, 0);
                acc = __builtin_amdgcn_mfma_f32_32x32x16_bf16(qh[ks], vl, acc, 0, 0, 0);
                acc = __builtin_amdgcn_mfma_f32_32x32x16_bf16(ql[ks], vh, acc, 0, 0, 0);
            }

            #pragma unroll
            for (int j = 0; j < 16; ++j) rmax[j] = fmaxf(rmax[j], acc[j]);
        }

        // cross-lane max over the 32 token-columns per q-row, then double-sum.
        double dsum = 0.0;
        #pragma unroll
        for (int j = 0; j < 16; ++j) {
            float m = rmax[j];
            m = fmaxf(m, __shfl_xor(m, 1));
            m = fmaxf(m, __shfl_xor(m, 2));
            m = fmaxf(m, __shfl_xor(m, 4));
            m = fmaxf(m, __shfl_xor(m, 8));
            m = fmaxf(m, __shfl_xor(m, 16));
            dsum += (double)m;
        }
        dsum += __shfl_xor(dsum, 32);
        if (lane == 0) scores[c] = (float)dsum;
    }
}

// ---------------- Kernel 3: per-batch top-100 (sorted desc) ----------------
__global__ __launch_bounds__(512) void topk_kernel(const float* __restrict__ scores,
                                                   const int* __restrict__ dpids,
                                                   const int* __restrict__ boundaries,
                                                   float* __restrict__ out) {
    __shared__ float ss[512];
    __shared__ int   sp[512];
    const int b = blockIdx.x;
    const int t = threadIdx.x;
    const int lo = boundaries[0];

    float sc = -__builtin_inff();
    int   p  = -1;
    if (t < NPIDS) {
        p = dpids[b * NPIDS + t];
        sc = (p < 0) ? -__builtin_inff() : scores[b * NPIDS + t];
    }
    ss[t] = sc;
    sp[t] = p;
    __syncthreads();

    for (int k = 2; k <= 512; k <<= 1) {
        for (int j = k >> 1; j > 0; j >>= 1) {
            int ixj = t ^ j;
            if (ixj > t) {
                float a = ss[t], c = ss[ixj];
                bool down = ((t & k) == 0);
                bool swap = down ? (a < c) : (a > c);
                if (swap) {
                    int pa = sp[t], pc = sp[ixj];
                    ss[t] = c;   ss[ixj] = a;
                    sp[t] = pc;  sp[ixj] = pa;
                }
            }
            __syncthreads();
        }
    }

    if (t < TOPK) {
        out[b * TOPK + t] = ss[t];
        int pp = sp[t];
        out[NB * TOPK + b * TOPK + t] = (pp >= 0) ? (float)(pp + lo) : -1.0f;
    }
}

// ---------------- launch ----------------
extern "C" void kernel_launch(void* const* d_in, const int* in_sizes, int n_in,
                              void* d_out, int out_size, void* d_ws, size_t ws_size,
                              hipStream_t stream) {
    const float* qv        = (const float*)d_in[0];
    const int*   pids      = (const int*)d_in[1];
    const float* vectors   = (const float*)d_in[2];
    const int*   boundaries= (const int*)d_in[3];

    int*   dpids  = (int*)d_ws;
    float* scores = (float*)((char*)d_ws + 32768);

    dedupe_kernel<<<NB, 512, 0, stream>>>(pids, boundaries, dpids);
    score_kernel <<<(NB * NPIDS) / 8, 256, 0, stream>>>(qv, vectors, dpids, scores);
    topk_kernel  <<<NB, 512, 0, stream>>>(scores, dpids, boundaries, (float*)d_out);
}